// Round 16
// baseline (432.027 us; speedup 1.0000x reference)
//
#include <hip/hip_runtime.h>
#include <math.h>

typedef __attribute__((ext_vector_type(8))) short short8;
typedef __attribute__((ext_vector_type(4))) float float4v;

#define KDIM  512
#define NQKV  1536

__device__ __forceinline__ unsigned short f2bf(float f) {
    unsigned int u = __float_as_uint(f);
    u += 0x7FFFu + ((u >> 16) & 1u);   // round-to-nearest-even
    return (unsigned short)(u >> 16);
}
__device__ __forceinline__ float bf2f(unsigned short u) {
    return __uint_as_float(((unsigned int)u) << 16);
}

// async global->LDS DMA, 16 B per lane; LDS dest = wave-uniform base + lane*16
__device__ __forceinline__ void gl2lds16(const unsigned short* g, unsigned short* l) {
    __builtin_amdgcn_global_load_lds(
        (const __attribute__((address_space(1))) void*)g,
        (__attribute__((address_space(3))) void*)l, 16, 0, 0);
}

// ---------------- fused cast: x (with roll -32) + both weight matrices ----------
// blocks [0, 16384): x cast+roll ; blocks [16384, 17408): w_qkv / w_proj cast
__global__ __launch_bounds__(256) void cast_all_kernel(const float* __restrict__ x,
                                                       const float* __restrict__ wqkv,
                                                       const float* __restrict__ wproj,
                                                       unsigned short* __restrict__ xb,
                                                       unsigned short* __restrict__ wqkvb,
                                                       unsigned short* __restrict__ wprojb) {
    if (blockIdx.x < 16384) {
        int tid = blockIdx.x * 256 + threadIdx.x;
        int t = tid >> 7;               // token row 0..32767 (shifted order)
        int c = (tid & 127) << 2;
        int b = t >> 12, n = t & 4095;
        int src = (b << 12) | ((n + 32) & 4095);    // roll(x, -32)
        float4 v = *(const float4*)(x + (((size_t)src) << 9) + c);
        ushort4 o;
        o.x = f2bf(v.x); o.y = f2bf(v.y); o.z = f2bf(v.z); o.w = f2bf(v.w);
        *(ushort4*)(xb + (((size_t)t) << 9) + c) = o;
    } else {
        int tid = (blockIdx.x - 16384) * 256 + threadIdx.x;
        int e = tid << 2;
        if (e < NQKV * KDIM) {
            float4 v = *(const float4*)(wqkv + e);
            ushort4 o; o.x = f2bf(v.x); o.y = f2bf(v.y); o.z = f2bf(v.z); o.w = f2bf(v.w);
            *(ushort4*)(wqkvb + e) = o;
        } else {
            int e2 = e - NQKV * KDIM;
            float4 v = *(const float4*)(wproj + e2);
            ushort4 o; o.x = f2bf(v.x); o.y = f2bf(v.y); o.z = f2bf(v.z); o.w = f2bf(v.w);
            *(ushort4*)(wprojb + e2) = o;
        }
    }
}

// ---------------- QKV GEMM: C[M,N] = A[M,K] @ B[N,K]^T ----------------
// 128x128 tile, BK=64 (32 MFMA per barrier pair), 4 waves (2x2).
// Staging via global_load_lds width=16 into flat row-major stride-64 LDS with an
// XOR col-block swizzle (applied on the GLOBAL address side, since the DMA's LDS
// destination must be lane-contiguous): stored block p at row r holds source
// col-block p^(r&7). Fragment ds_read_b128 then hits 8 distinct bank groups.
// NOTE: reg-staged A (fused f32 cast) was tried and is a measured LOSS (103 vs
// 72 us): mixing reg-loads with DMA defeats the vmcnt scheduling (cf. m151).
// Partial software-pipelining of this structure is also a measured no-op
// (m99/m100/m131/m139) - only the full 8-phase template breaks the ceiling.
// XCD-aware bijective swizzle: nwg%8==0; blocks sharing an A-panel (same bm)
// land on the same XCD -> A fetched ~once from HBM (FETCH 135 -> ~30 MB).
template<int N>
__global__ __launch_bounds__(256, 2) void gemm_kernel(
        const unsigned short* __restrict__ A,
        const unsigned short* __restrict__ B,
        unsigned short* __restrict__ Cb) {
    __shared__ __align__(16) unsigned short As[128 * 64];
    __shared__ __align__(16) unsigned short Bs[128 * 64];
    constexpr int GX  = N / 128;         // blocks along n: 12 (QKV)
    constexpr int PER = (GX * 256) / 8;  // blocks per XCD (exact: nwg % 8 == 0)
    const int wgid = blockIdx.y * GX + blockIdx.x;          // dispatch-linear
    const int swz  = (wgid & 7) * PER + (wgid >> 3);        // bijective chunking
    const int bm = swz / GX;
    const int bn = swz % GX;

    const int tid = threadIdx.x;
    const int wave = tid >> 6, lane = tid & 63;
    const int quad = lane >> 4, l16 = lane & 15;
    const int wm = (wave >> 1) * 64, wn = (wave & 1) * 64;
    // DMA: chunk = 8 rows x 64 cols = 1 KB. Lane covers row chunk*8+(lane>>3),
    // stored col-block lane&7, which must hold source col-block (lane&7)^(row&7).
    const int srow = lane >> 3;                  // 0..7 within chunk
    const int scol = ((lane & 7) ^ srow) * 8;    // swizzled source column

    float4v acc[4][4] = {};

    const unsigned short* Abase = A + (size_t)(bm * 128) * KDIM;
    const unsigned short* Bbase = B + (size_t)(bn * 128) * KDIM;

    for (int k0 = 0; k0 < KDIM; k0 += 64) {
        #pragma unroll
        for (int j = 0; j < 4; j++) {
            int chunk = j * 4 + wave;               // 0..15
            int row = chunk * 8 + srow;             // 0..127
            gl2lds16(Abase + (size_t)row * KDIM + k0 + scol, As + chunk * 512);
            gl2lds16(Bbase + (size_t)row * KDIM + k0 + scol, Bs + chunk * 512);
        }
        __syncthreads();
        #pragma unroll
        for (int ki = 0; ki < 2; ki++) {
            short8 af[4], bf[4];
            #pragma unroll
            for (int mi = 0; mi < 4; mi++) {
                int r = wm + mi * 16 + l16;
                int blk = (ki * 4 + quad) ^ (l16 & 7);
                af[mi] = *(const short8*)(As + r * 64 + blk * 8);
            }
            #pragma unroll
            for (int ni = 0; ni < 4; ni++) {
                int r = wn + ni * 16 + l16;
                int blk = (ki * 4 + quad) ^ (l16 & 7);
                bf[ni] = *(const short8*)(Bs + r * 64 + blk * 8);
            }
            #pragma unroll
            for (int mi = 0; mi < 4; mi++)
                #pragma unroll
                for (int ni = 0; ni < 4; ni++)
                    acc[mi][ni] = __builtin_amdgcn_mfma_f32_16x16x32_bf16(
                        af[mi], bf[ni], acc[mi][ni], 0, 0, 0);
        }
        __syncthreads();
    }

    #pragma unroll
    for (int mi = 0; mi < 4; mi++) {
        #pragma unroll
        for (int r = 0; r < 4; r++) {
            int m = bm * 128 + wm + mi * 16 + quad * 4 + r;
            #pragma unroll
            for (int ni = 0; ni < 4; ni++) {
                int n = bn * 128 + wn + ni * 16 + l16;
                Cb[(size_t)m * N + n] = f2bf(acc[mi][ni][r]);
            }
        }
    }
}

// ------- fused attention + projection, one WINDOW per block, 4 pipelined chunks
// Post-mortems: r7 (no-LDS) 100us = scattered-gather latency; r10 (2x32-token
// chunks, 131KB LDS) 77us = serial stage->drain->compute at 1 block/CU; r12
// (half-window, 66KB) 108us = same chain, 2x staged bytes + 2x barriers.
// This version exploits: 16 consecutive tokens complete 16 ENTIRE proj rows
// (r = h*8 + w/8, 2 w-groups x 8 heads) -> proj runs PER CHUNK, Asf = 16 rows
// = 16 KB. Per chunk: attn(c) -> barrier -> issue STAGE(c+1) -> proj-GEMM(c)
// (64 MFMA/wave ~ 512+ cy hides the DMA) -> barrier(drain). Single KV buffer
// (16 tokens x 1024 elems = 32 KB), un-padded, XOR-swizzled: linear DMA dest +
// pre-swizzled global source (unit u of row r holds source unit u^(r&7)) +
// same XOR on reads (rule-21 both-sides pattern). Bank spread verified:
// K/V reads (tl,dq lanes) 8 distinct groups; Asf writes/reads via
// key(r) = (r^(r>>3))&7 uniform 8/group. LDS 48 KB + launch_bounds(512,4)
// -> 2 blocks/CU (16 waves, 2x r10) AND stage hidden under MFMA.
__global__ __launch_bounds__(512, 4) void attnproj_kernel(
        const unsigned short* __restrict__ qkvb,
        const unsigned short* __restrict__ wprojb,
        const float* __restrict__ bias,
        float* __restrict__ out) {
    __shared__ __align__(16) unsigned short Asf[16 * 512];   // 16 KB
    __shared__ __align__(16) unsigned short KV[16 * 1024];   // 32 KB
    const int tid = threadIdx.x;
    const int bid = blockIdx.x;                    // 512 blocks
    const int win = (bid & 7) * 64 + (bid >> 3);   // XCD-bijective (512%8==0)

    const int dq = tid & 3;          // 16-elem d-quarter
    const int h  = (tid >> 2) & 7;   // head
    const int tl = tid >> 5;         // token 0..15 within chunk
    const int tkey = tl & 7;

    const int wave = tid >> 6, lane = tid & 63;
    const int quad = lane >> 4, l16 = lane & 15;

    // hoisted Q loads (4 chunks x 32 elems for this thread's (h, dq-half))
    short8 q0[4], q1[4];
    #pragma unroll
    for (int c = 0; c < 4; c++) {
        const unsigned short* qsrc =
            qkvb + (size_t)(win * 64 + c * 16 + tl) * NQKV + h * 64 + dq * 16;
        q0[c] = *(const short8*)qsrc;
        q1[c] = *(const short8*)(qsrc + 8);
    }
    // hoisted bias for this lane's proj columns
    float bias_r[4];
    #pragma unroll
    for (int ni = 0; ni < 4; ni++)
        bias_r[ni] = bias[wave * 64 + ni * 16 + l16];

    // stage chunk 0: 2048 slots x 16 B; row = slot>>7, unit u = slot&127;
    // LDS dest linear (wave covers one half-row: uniform base + lane*16);
    // source pre-swizzled: physical unit u holds logical unit u^(row&7).
    #pragma unroll
    for (int i = 0; i < 4; i++) {
        int slot = i * 512 + tid, row = slot >> 7, u = slot & 127;
        gl2lds16(qkvb + (size_t)(win * 64 + row) * NQKV + 512 + (u ^ (row & 7)) * 8,
                 KV + row * 1024 + u * 8);
    }
    __syncthreads();

    #pragma unroll
    for (int c = 0; c < 4; c++) {
        // ---------------- attention on chunk c ----------------
        float qv[16];
        #pragma unroll
        for (int j = 0; j < 8; j++) {
            qv[j]     = bf2f((unsigned short)q0[c][j]);
            qv[8 + j] = bf2f((unsigned short)q1[c][j]);
        }
        const unsigned short* krow = KV + tl * 1024;

        float s[8];
        #pragma unroll
        for (int g = 0; g < 8; g++) {
            int lu = g * 8 + dq * 2;                 // logical 8-elem unit (K)
            short8 k0 = *(const short8*)(krow + ((lu ^ tkey) * 8));
            short8 k1 = *(const short8*)(krow + (((lu + 1) ^ tkey) * 8));
            float acc = 0.f;
            #pragma unroll
            for (int j = 0; j < 8; j++)
                acc += qv[j] * bf2f((unsigned short)k0[j])
                     + qv[8 + j] * bf2f((unsigned short)k1[j]);
            acc += __shfl_xor(acc, 1);               // merge dq group (4 lanes)
            acc += __shfl_xor(acc, 2);
            s[g] = acc;
        }

        float mx = s[0];
        #pragma unroll
        for (int g = 1; g < 8; g++) mx = fmaxf(mx, s[g]);
        float p[8], sum = 0.f;
        #pragma unroll
        for (int g = 0; g < 8; g++) { p[g] = __expf((s[g] - mx) * 0.125f); sum += p[g]; }
        float inv = 1.f / sum;
        #pragma unroll
        for (int g = 0; g < 8; g++) p[g] *= inv;

        float o[16];
        #pragma unroll
        for (int j = 0; j < 16; j++) o[j] = 0.f;
        #pragma unroll
        for (int g = 0; g < 8; g++) {
            int lu = 64 + g * 8 + dq * 2;            // logical unit (V)
            short8 v0 = *(const short8*)(krow + ((lu ^ tkey) * 8));
            short8 v1 = *(const short8*)(krow + (((lu + 1) ^ tkey) * 8));
            #pragma unroll
            for (int j = 0; j < 8; j++) {
                o[j]     += p[g] * bf2f((unsigned short)v0[j]);
                o[8 + j] += p[g] * bf2f((unsigned short)v1[j]);
            }
        }

        // Asf write: local proj row lr = h*2 + (tl>>3); cols (tl&7)*64 + dq*16..
        {
            int lr = h * 2 + (tl >> 3);
            int key2 = (lr ^ (lr >> 3)) & 7;
            int cb = tkey * 8 + dq * 2;              // logical col-block 0..63
            short8 pk0, pk1;
            #pragma unroll
            for (int j = 0; j < 8; j++) {
                pk0[j] = (short)f2bf(o[j]);
                pk1[j] = (short)f2bf(o[8 + j]);
            }
            *(short8*)(Asf + lr * 512 + ((cb ^ key2) * 8)) = pk0;
            *(short8*)(Asf + lr * 512 + (((cb + 1) ^ key2) * 8)) = pk1;
        }
        __syncthreads();                             // Asf ready; KV free

        // prefetch next chunk's KV: issued NOW, drains at the barrier below --
        // the proj GEMM's MFMA+W-loads run while the DMA is in flight.
        if (c < 3) {
            #pragma unroll
            for (int i = 0; i < 4; i++) {
                int slot = i * 512 + tid, row = slot >> 7, u = slot & 127;
                gl2lds16(qkvb + (size_t)(win * 64 + (c + 1) * 16 + row) * NQKV
                                + 512 + (u ^ (row & 7)) * 8,
                         KV + row * 1024 + u * 8);
            }
        }

        // ---------------- proj GEMM on chunk c's 16 rows ----------------
        float4v acc2[4] = {};
        #pragma unroll
        for (int ks = 0; ks < 16; ks++) {
            int kb = ks * 4 + quad;
            short8 af = *(const short8*)(Asf + l16 * 512 +
                            ((kb ^ ((l16 ^ (l16 >> 3)) & 7)) * 8));
            #pragma unroll
            for (int ni = 0; ni < 4; ni++) {
                short8 bfr = *(const short8*)(wprojb +
                    (size_t)(wave * 64 + ni * 16 + l16) * KDIM + ks * 32 + quad * 8);
                acc2[ni] = __builtin_amdgcn_mfma_f32_16x16x32_bf16(
                    af, bfr, acc2[ni], 0, 0, 0);
            }
        }

        // epilogue: local row lr2 -> global proj row; bias + roll(+32) + f32 store
        #pragma unroll
        for (int r4 = 0; r4 < 4; r4++) {
            int lr2 = quad * 4 + r4;                 // 0..15
            int gm = win * 64 + (lr2 >> 1) * 8 + 2 * c + (lr2 & 1);
            int b = gm >> 12, pp = gm & 4095;
            int nrow = (pp + 32) & 4095;             // roll(out, +32)
            float* orow = out + (((size_t)((b << 12) | nrow)) << 9);
            #pragma unroll
            for (int ni = 0; ni < 4; ni++)
                orow[wave * 64 + ni * 16 + l16] = acc2[ni][r4] + bias_r[ni];
        }
        __syncthreads();                             // drains prefetch; Asf reusable
    }
}

extern "C" void kernel_launch(void* const* d_in, const int* in_sizes, int n_in,
                              void* d_out, int out_size, void* d_ws, size_t ws_size,
                              hipStream_t stream) {
    const float* x      = (const float*)d_in[0];
    const float* w_qkv  = (const float*)d_in[1];
    const float* w_proj = (const float*)d_in[2];
    const float* b_proj = (const float*)d_in[3];
    float* out = (float*)d_out;

    char* ws = (char*)d_ws;
    unsigned short* xb     = (unsigned short*)(ws);                 // 32 MB
    unsigned short* wqkvb  = (unsigned short*)(ws + 33554432);      // 1.5 MB
    unsigned short* wprojb = (unsigned short*)(ws + 35127296);      // 0.5 MB
    unsigned short* qkvb   = (unsigned short*)(ws + 35651584);      // 96 MB

    cast_all_kernel<<<17408, 256, 0, stream>>>(x, w_qkv, w_proj, xb, wqkvb, wprojb);
    gemm_kernel<NQKV><<<dim3(12, 256), 256, 0, stream>>>(xb, wqkvb, qkvb);
    attnproj_kernel<<<512, 512, 0, stream>>>(qkvb, wprojb, b_proj, out);
}

// Round 17
// 234.133 us; speedup vs baseline: 1.8452x; 1.8452x over previous
//
#include <hip/hip_runtime.h>
#include <math.h>

typedef __attribute__((ext_vector_type(8))) short short8;
typedef __attribute__((ext_vector_type(4))) float float4v;

#define KDIM  512
#define NQKV  1536

__device__ __forceinline__ unsigned short f2bf(float f) {
    unsigned int u = __float_as_uint(f);
    u += 0x7FFFu + ((u >> 16) & 1u);   // round-to-nearest-even
    return (unsigned short)(u >> 16);
}
__device__ __forceinline__ float bf2f(unsigned short u) {
    return __uint_as_float(((unsigned int)u) << 16);
}

// async global->LDS DMA, 16 B per lane; LDS dest = wave-uniform base + lane*16
__device__ __forceinline__ void gl2lds16(const unsigned short* g, unsigned short* l) {
    __builtin_amdgcn_global_load_lds(
        (const __attribute__((address_space(1))) void*)g,
        (__attribute__((address_space(3))) void*)l, 16, 0, 0);
}

// ---------------- fused cast: x (with roll -32) + both weight matrices ----------
// blocks [0, 16384): x cast+roll ; blocks [16384, 17408): w_qkv / w_proj cast
__global__ __launch_bounds__(256) void cast_all_kernel(const float* __restrict__ x,
                                                       const float* __restrict__ wqkv,
                                                       const float* __restrict__ wproj,
                                                       unsigned short* __restrict__ xb,
                                                       unsigned short* __restrict__ wqkvb,
                                                       unsigned short* __restrict__ wprojb) {
    if (blockIdx.x < 16384) {
        int tid = blockIdx.x * 256 + threadIdx.x;
        int t = tid >> 7;               // token row 0..32767 (shifted order)
        int c = (tid & 127) << 2;
        int b = t >> 12, n = t & 4095;
        int src = (b << 12) | ((n + 32) & 4095);    // roll(x, -32)
        float4 v = *(const float4*)(x + (((size_t)src) << 9) + c);
        ushort4 o;
        o.x = f2bf(v.x); o.y = f2bf(v.y); o.z = f2bf(v.z); o.w = f2bf(v.w);
        *(ushort4*)(xb + (((size_t)t) << 9) + c) = o;
    } else {
        int tid = (blockIdx.x - 16384) * 256 + threadIdx.x;
        int e = tid << 2;
        if (e < NQKV * KDIM) {
            float4 v = *(const float4*)(wqkv + e);
            ushort4 o; o.x = f2bf(v.x); o.y = f2bf(v.y); o.z = f2bf(v.z); o.w = f2bf(v.w);
            *(ushort4*)(wqkvb + e) = o;
        } else {
            int e2 = e - NQKV * KDIM;
            float4 v = *(const float4*)(wproj + e2);
            ushort4 o; o.x = f2bf(v.x); o.y = f2bf(v.y); o.z = f2bf(v.z); o.w = f2bf(v.w);
            *(ushort4*)(wprojb + e2) = o;
        }
    }
}

// ---------------- GEMM: C[M,N] = A[M,K] @ B[N,K]^T ----------------
// 128x128 tile, BK=64 (32 MFMA per barrier pair), 4 waves (2x2).
// Staging via global_load_lds width=16 into flat row-major stride-64 LDS with an
// XOR col-block swizzle (applied on the GLOBAL address side, since the DMA's LDS
// destination must be lane-contiguous): stored block p at row r holds source
// col-block p^(r&7). Fragment ds_read_b128 then hits 8 distinct bank groups.
// MEASURED HISTORY (do not retry): reg-staged A w/ fused f32 cast = 103 us vs
// 72 (m151 pattern); attn+proj fusion variants = 248/253/256/432 us vs this
// split pipeline's 241.9; per-chunk proj re-reads W 4x/block -> 255 MB L2-fill
// + 318 MB RMW-amplified writes (r16). XCD-aware bijective swizzle: nwg%8==0;
// blocks sharing an A-panel (same bm) land on one XCD -> A fetched ~once
// (FETCH 135 -> 28.6 MB, QKV 60 us @ MfmaUtil 37% = m97-structure ceiling).
template<int N, bool PROJ>
__global__ __launch_bounds__(256, 2) void gemm_kernel(
        const unsigned short* __restrict__ A,
        const unsigned short* __restrict__ B,
        unsigned short* __restrict__ Cb,
        float* __restrict__ Cf,
        const float* __restrict__ bias) {
    __shared__ __align__(16) unsigned short As[128 * 64];
    __shared__ __align__(16) unsigned short Bs[128 * 64];
    constexpr int GX  = N / 128;         // blocks along n: 12 (QKV) or 4 (proj)
    constexpr int PER = (GX * 256) / 8;  // blocks per XCD (exact: nwg % 8 == 0)
    const int wgid = blockIdx.y * GX + blockIdx.x;          // dispatch-linear
    const int swz  = (wgid & 7) * PER + (wgid >> 3);        // bijective chunking
    const int bm = swz / GX;
    const int bn = swz % GX;

    const int tid = threadIdx.x;
    const int wave = tid >> 6, lane = tid & 63;
    const int quad = lane >> 4, l16 = lane & 15;
    const int wm = (wave >> 1) * 64, wn = (wave & 1) * 64;
    // DMA: chunk = 8 rows x 64 cols = 1 KB. Lane covers row chunk*8+(lane>>3),
    // stored col-block lane&7, which must hold source col-block (lane&7)^(row&7).
    const int srow = lane >> 3;                  // 0..7 within chunk
    const int scol = ((lane & 7) ^ srow) * 8;    // swizzled source column

    float4v acc[4][4] = {};

    const unsigned short* Abase = A + (size_t)(bm * 128) * KDIM;
    const unsigned short* Bbase = B + (size_t)(bn * 128) * KDIM;

    for (int k0 = 0; k0 < KDIM; k0 += 64) {
        #pragma unroll
        for (int j = 0; j < 4; j++) {
            int chunk = j * 4 + wave;               // 0..15
            int row = chunk * 8 + srow;             // 0..127
            gl2lds16(Abase + (size_t)row * KDIM + k0 + scol, As + chunk * 512);
            gl2lds16(Bbase + (size_t)row * KDIM + k0 + scol, Bs + chunk * 512);
        }
        __syncthreads();
        #pragma unroll
        for (int ki = 0; ki < 2; ki++) {
            short8 af[4], bf[4];
            #pragma unroll
            for (int mi = 0; mi < 4; mi++) {
                int r = wm + mi * 16 + l16;
                int blk = (ki * 4 + quad) ^ (l16 & 7);
                af[mi] = *(const short8*)(As + r * 64 + blk * 8);
            }
            #pragma unroll
            for (int ni = 0; ni < 4; ni++) {
                int r = wn + ni * 16 + l16;
                int blk = (ki * 4 + quad) ^ (l16 & 7);
                bf[ni] = *(const short8*)(Bs + r * 64 + blk * 8);
            }
            #pragma unroll
            for (int mi = 0; mi < 4; mi++)
                #pragma unroll
                for (int ni = 0; ni < 4; ni++)
                    acc[mi][ni] = __builtin_amdgcn_mfma_f32_16x16x32_bf16(
                        af[mi], bf[ni], acc[mi][ni], 0, 0, 0);
        }
        __syncthreads();
    }

    #pragma unroll
    for (int mi = 0; mi < 4; mi++) {
        #pragma unroll
        for (int r = 0; r < 4; r++) {
            int m = bm * 128 + wm + mi * 16 + quad * 4 + r;
            if (!PROJ) {
                #pragma unroll
                for (int ni = 0; ni < 4; ni++) {
                    int n = bn * 128 + wn + ni * 16 + l16;
                    Cb[(size_t)m * N + n] = f2bf(acc[mi][ni][r]);
                }
            } else {
                int b = m >> 12, p = m & 4095;
                int nrow = (p + 32) & 4095;      // roll(out, +32)
                float* orow = Cf + (((size_t)((b << 12) | nrow)) << 9);
                #pragma unroll
                for (int ni = 0; ni < 4; ni++) {
                    int n = bn * 128 + wn + ni * 16 + l16;
                    orow[n] = acc[mi][ni][r] + bias[n];
                }
            }
        }
    }
}

// ---------------- attention: 8x8 attention OVER HEADS per token ----------------
// einsum('bwhd,bwgd->bwhg'): per (window,position) token, S[h][g] = Q_h . K_g,
// softmax over g (scale 0.125), O[h] = sum_g P[h][g] V[g].
// One thread per (token, head); block = 128 threads = 16 tokens x 8 heads.
// Only K,V staged in LDS (padded stride -> conflict-free); Q loaded straight
// to registers from global, issued before staging so the loads overlap.
// MEASURED: this structure beat no-LDS (r5), window-fused (r7/r10/r12), and
// per-chunk-pipelined (r16) variants -- best total 241.9 us.
#define TPB_TOK 16
#define KV_STRIDE 1032   // 1024 + 8: token stride = 2064 B = 516 dw = 4 banks
__global__ __launch_bounds__(128) void attn_kernel(const unsigned short* __restrict__ qkvb,
                                                   unsigned short* __restrict__ aob) {
    __shared__ __align__(16) unsigned short smem[TPB_TOK * KV_STRIDE];
    const int tid = threadIdx.x;
    const int t0 = blockIdx.x * TPB_TOK;
    const int tok = tid >> 3, h = tid & 7;
    const int t = t0 + tok;

    // Q[h][0..63] global loads issue first (overlap with K/V staging)
    short8 qs[8];
    {
        const unsigned short* qsrc = qkvb + (size_t)t * NQKV + h * 64;
        #pragma unroll
        for (int dc = 0; dc < 8; dc++)
            qs[dc] = *(const short8*)(qsrc + dc * 8);
    }

    // stage K,V (rows of 1024 bf16 per token) into LDS, coalesced short8
    {
        int r = tid >> 3, cb = (tid & 7) * 8;
        const unsigned short* src = qkvb + (size_t)(t0 + r) * NQKV + 512;
        unsigned short* dst = smem + r * KV_STRIDE;
        #pragma unroll
        for (int p = 0; p < 16; p++) {
            int c = cb + p * 64;
            *(short8*)(dst + c) = *(const short8*)(src + c);
        }
    }
    __syncthreads();

    const unsigned short* row = smem + tok * KV_STRIDE;

    float qv[64];
    #pragma unroll
    for (int dc = 0; dc < 8; dc++)
        #pragma unroll
        for (int j = 0; j < 8; j++)
            qv[dc * 8 + j] = bf2f((unsigned short)qs[dc][j]);

    // S[g] = Q_h . K_g  (K reads h-independent -> LDS broadcast across 8 lanes)
    float s[8];
    #pragma unroll
    for (int g = 0; g < 8; g++) {
        float acc = 0.f;
        #pragma unroll
        for (int dc = 0; dc < 8; dc++) {
            short8 ks = *(const short8*)(row + g * 64 + dc * 8);
            #pragma unroll
            for (int j = 0; j < 8; j++)
                acc += qv[dc * 8 + j] * bf2f((unsigned short)ks[j]);
        }
        s[g] = acc;
    }

    float mx = s[0];
    #pragma unroll
    for (int g = 1; g < 8; g++) mx = fmaxf(mx, s[g]);
    float p[8], sum = 0.f;
    #pragma unroll
    for (int g = 0; g < 8; g++) { p[g] = __expf((s[g] - mx) * 0.125f); sum += p[g]; }
    float inv = 1.f / sum;
    #pragma unroll
    for (int g = 0; g < 8; g++) p[g] *= inv;

    float o[64];
    #pragma unroll
    for (int j = 0; j < 64; j++) o[j] = 0.f;
    #pragma unroll
    for (int g = 0; g < 8; g++) {
        #pragma unroll
        for (int dc = 0; dc < 8; dc++) {
            short8 vs = *(const short8*)(row + 512 + g * 64 + dc * 8);
            #pragma unroll
            for (int j = 0; j < 8; j++)
                o[dc * 8 + j] += p[g] * bf2f((unsigned short)vs[j]);
        }
    }

    // scrambled write replicating transpose(0,2,1,3).reshape:
    // proj-in row = win*64 + h*8 + w/8 ; col = (w%8)*64 + d
    int win = t >> 6, w = t & 63;
    unsigned short* dst = aob + (size_t)(win * 64 + h * 8 + (w >> 3)) * 512 + (w & 7) * 64;
    #pragma unroll
    for (int dc = 0; dc < 16; dc++) {
        ushort4 ov;
        ov.x = f2bf(o[dc * 4 + 0]); ov.y = f2bf(o[dc * 4 + 1]);
        ov.z = f2bf(o[dc * 4 + 2]); ov.w = f2bf(o[dc * 4 + 3]);
        *(ushort4*)(dst + dc * 4) = ov;
    }
}

extern "C" void kernel_launch(void* const* d_in, const int* in_sizes, int n_in,
                              void* d_out, int out_size, void* d_ws, size_t ws_size,
                              hipStream_t stream) {
    const float* x      = (const float*)d_in[0];
    const float* w_qkv  = (const float*)d_in[1];
    const float* w_proj = (const float*)d_in[2];
    const float* b_proj = (const float*)d_in[3];
    float* out = (float*)d_out;

    char* ws = (char*)d_ws;
    unsigned short* xb     = (unsigned short*)(ws);                 // 32 MB
    unsigned short* wqkvb  = (unsigned short*)(ws + 33554432);      // 1.5 MB
    unsigned short* wprojb = (unsigned short*)(ws + 35127296);      // 0.5 MB
    unsigned short* qkvb   = (unsigned short*)(ws + 35651584);      // 96 MB
    unsigned short* aob    = (unsigned short*)(ws + 136314880);     // 32 MB

    cast_all_kernel<<<17408, 256, 0, stream>>>(x, w_qkv, w_proj, xb, wqkvb, wprojb);
    gemm_kernel<NQKV, false><<<dim3(12, 256), 256, 0, stream>>>(xb, wqkvb, qkvb, nullptr, nullptr);
    attn_kernel<<<2048, 128, 0, stream>>>(qkvb, aob);
    gemm_kernel<512, true><<<dim3(4, 256), 256, 0, stream>>>(aob, wprojb, nullptr, out, b_proj);
}